// Round 1
// baseline (2238.578 us; speedup 1.0000x reference)
//
#include <hip/hip_runtime.h>

#define SEQ    2048
#define NHEAD  16
#define HD     64
#define EMB    1024
#define NBATCH 4
#define MTOT   (NBATCH * SEQ)   // 8192

// ---------------------------------------------------------------------------
// Tiled fp32 GEMM: C[m][n] = sum_k A[m][k] * W[k][n] + bias[n]
// A: [MTOT, EMB] row-major, W: [EMB, EMB] row-major, C: [MTOT, EMB].
// 64x64 output tile, TK=16, 256 threads, 4x4 microtile per thread.
// LDS stride 68 floats (=272B, 16B-aligned rows, breaks power-of-2 banks).
// ---------------------------------------------------------------------------
__device__ __forceinline__ void gemm_body(
    const float* __restrict__ A, const float* __restrict__ W,
    const float* __restrict__ bias, float* __restrict__ C)
{
  __shared__ float As[16][68];   // As[k][m] (A tile transposed)
  __shared__ float Bs[16][68];   // Bs[k][n]
  const int tid = threadIdx.x;
  const int tx = tid & 15, ty = tid >> 4;
  const int m0 = blockIdx.x * 64, n0 = blockIdx.y * 64;
  const int alr = tid >> 2;          // A row within tile (0..63)
  const int alc = (tid & 3) * 4;     // A k-col start (0,4,8,12)
  const int bkr = tid >> 4;          // B k-row (0..15)
  const int bnc = (tid & 15) * 4;    // B n-col start

  float acc[4][4] = {};

  for (int k0 = 0; k0 < EMB; k0 += 16) {
    __syncthreads();
    // A tile 64x16 -> As[k][m] (transposed), float4 global load
    float4 a4 = *(const float4*)(A + (size_t)(m0 + alr) * EMB + k0 + alc);
    As[alc + 0][alr] = a4.x;
    As[alc + 1][alr] = a4.y;
    As[alc + 2][alr] = a4.z;
    As[alc + 3][alr] = a4.w;
    // B tile 16x64 -> Bs[k][n], float4 both sides
    *(float4*)&Bs[bkr][bnc] =
        *(const float4*)(W + (size_t)(k0 + bkr) * EMB + n0 + bnc);
    __syncthreads();

    #pragma unroll
    for (int kk = 0; kk < 16; ++kk) {
      float4 av = *(const float4*)&As[kk][4 * ty];
      float4 bv = *(const float4*)&Bs[kk][4 * tx];
      const float aa[4] = {av.x, av.y, av.z, av.w};
      const float bb[4] = {bv.x, bv.y, bv.z, bv.w};
      #pragma unroll
      for (int i = 0; i < 4; ++i)
        #pragma unroll
        for (int j = 0; j < 4; ++j)
          acc[i][j] += aa[i] * bb[j];
    }
  }

  #pragma unroll
  for (int i = 0; i < 4; ++i) {
    const int m = m0 + 4 * ty + i;
    const int n = n0 + 4 * tx;
    float4 o;
    o.x = acc[i][0] + bias[n + 0];
    o.y = acc[i][1] + bias[n + 1];
    o.z = acc[i][2] + bias[n + 2];
    o.w = acc[i][3] + bias[n + 3];
    *(float4*)(C + (size_t)m * EMB + n) = o;
  }
}

__global__ __launch_bounds__(256) void qkv_gemm_kernel(
    const float* __restrict__ x,
    const float* __restrict__ Wq, const float* __restrict__ bq,
    const float* __restrict__ Wk, const float* __restrict__ bk,
    const float* __restrict__ Wv, const float* __restrict__ bv,
    float* __restrict__ q, float* __restrict__ k, float* __restrict__ v)
{
  const int w = blockIdx.z;
  const float* W = (w == 0) ? Wq : (w == 1) ? Wk : Wv;
  const float* b = (w == 0) ? bq : (w == 1) ? bk : bv;
  float* C       = (w == 0) ? q  : (w == 1) ? k  : v;
  gemm_body(x, W, b, C);
}

__global__ __launch_bounds__(256) void proj_gemm_kernel(
    const float* __restrict__ att, const float* __restrict__ Wo,
    const float* __restrict__ bo, float* __restrict__ out)
{
  gemm_body(att, Wo, bo, out);
}

// ---------------------------------------------------------------------------
// Causal flash attention, fp32.
// Q/K/V/O all stored [B, T, H, D] (row t of head h at ((b*T+t)*H+h)*D).
// Block: 256 threads handles one (b,h) x 64-row Q tile; loops over KV tiles
// of 64 with online softmax. Thread (tx,ty) owns rows 4ty..+3, cols 4tx..+3.
// P tile aliases the K tile (K fully consumed before P is written).
// ---------------------------------------------------------------------------
__global__ __launch_bounds__(256) void flash_attn_kernel(
    const float* __restrict__ Q, const float* __restrict__ K,
    const float* __restrict__ V, float* __restrict__ O)
{
  __shared__ float Qs[64][68];
  __shared__ float Ks[64][68];   // reused as P tile after S-compute
  __shared__ float Vs[64][68];
  float (* const Ps)[68] = Ks;

  const int tid = threadIdx.x;
  const int tx = tid & 15, ty = tid >> 4;
  const int qt = (int)gridDim.x - 1 - (int)blockIdx.x;  // heavy tiles first
  const int bh = blockIdx.y;
  const int b = bh >> 4, h = bh & 15;
  const int t0 = qt * 64;
  const size_t headbase = ((size_t)b * SEQ * NHEAD + h) * HD;
  const int lr = tid >> 2;          // loader row (0..63)
  const int lc = (tid & 3) * 16;    // loader col start

  // Load Q tile once
  {
    const float* qrow = Q + headbase + (size_t)(t0 + lr) * (NHEAD * HD) + lc;
    #pragma unroll
    for (int j = 0; j < 4; ++j)
      *(float4*)&Qs[lr][lc + 4 * j] = *(const float4*)(qrow + 4 * j);
  }

  float m_i[4], l_i[4], oa[4][4];
  #pragma unroll
  for (int i = 0; i < 4; ++i) {
    m_i[i] = -1e30f;
    l_i[i] = 0.f;
    #pragma unroll
    for (int j = 0; j < 4; ++j) oa[i][j] = 0.f;
  }
  const float scale = 0.125f;   // 1/sqrt(64)

  for (int kt = 0; kt <= qt; ++kt) {
    __syncthreads();   // prior iter's P/V reads done before overwrite
    {
      const float* krow = K + headbase + (size_t)(kt * 64 + lr) * (NHEAD * HD) + lc;
      const float* vrow = V + headbase + (size_t)(kt * 64 + lr) * (NHEAD * HD) + lc;
      #pragma unroll
      for (int j = 0; j < 4; ++j) {
        *(float4*)&Ks[lr][lc + 4 * j] = *(const float4*)(krow + 4 * j);
        *(float4*)&Vs[lr][lc + 4 * j] = *(const float4*)(vrow + 4 * j);
      }
    }
    __syncthreads();

    // S[i][j] = sum_d Q[row] . K[col]
    float s[4][4] = {};
    #pragma unroll
    for (int d4 = 0; d4 < 16; ++d4) {
      float qa[4][4], kb[4][4];
      #pragma unroll
      for (int i = 0; i < 4; ++i) {
        float4 t4 = *(const float4*)&Qs[4 * ty + i][4 * d4];
        qa[i][0] = t4.x; qa[i][1] = t4.y; qa[i][2] = t4.z; qa[i][3] = t4.w;
      }
      #pragma unroll
      for (int j = 0; j < 4; ++j) {
        float4 t4 = *(const float4*)&Ks[4 * tx + j][4 * d4];
        kb[j][0] = t4.x; kb[j][1] = t4.y; kb[j][2] = t4.z; kb[j][3] = t4.w;
      }
      #pragma unroll
      for (int i = 0; i < 4; ++i)
        #pragma unroll
        for (int j = 0; j < 4; ++j)
          #pragma unroll
          for (int c = 0; c < 4; ++c)
            s[i][j] += qa[i][c] * kb[j][c];
    }

    __syncthreads();   // all S reads of Ks done before P overwrites it

    // mask + online softmax (row groups = 16 consecutive lanes)
    const bool diag = (kt == qt);
    #pragma unroll
    for (int i = 0; i < 4; ++i) {
      const int qr = 4 * ty + i;   // local q row
      float sv[4];
      float rowmax = -1e30f;
      #pragma unroll
      for (int j = 0; j < 4; ++j) {
        const int kc = 4 * tx + j;
        float val = s[i][j] * scale;
        if (diag && kc > qr) val = -1e30f;   // causal
        sv[j] = val;
        rowmax = fmaxf(rowmax, val);
      }
      #pragma unroll
      for (int off = 1; off < 16; off <<= 1)
        rowmax = fmaxf(rowmax, __shfl_xor(rowmax, off, 16));
      const float mnew = fmaxf(m_i[i], rowmax);
      const float corr = __expf(m_i[i] - mnew);
      float psum = 0.f;
      #pragma unroll
      for (int j = 0; j < 4; ++j) { sv[j] = __expf(sv[j] - mnew); psum += sv[j]; }
      #pragma unroll
      for (int off = 1; off < 16; off <<= 1)
        psum += __shfl_xor(psum, off, 16);
      l_i[i] = l_i[i] * corr + psum;
      m_i[i] = mnew;
      #pragma unroll
      for (int j = 0; j < 4; ++j) oa[i][j] *= corr;
      *(float4*)&Ps[qr][4 * tx] = make_float4(sv[0], sv[1], sv[2], sv[3]);
    }
    __syncthreads();

    // O += P @ V
    #pragma unroll
    for (int c4 = 0; c4 < 16; ++c4) {
      float pr[4][4];
      #pragma unroll
      for (int i = 0; i < 4; ++i) {
        float4 t4 = *(const float4*)&Ps[4 * ty + i][4 * c4];
        pr[i][0] = t4.x; pr[i][1] = t4.y; pr[i][2] = t4.z; pr[i][3] = t4.w;
      }
      #pragma unroll
      for (int cc = 0; cc < 4; ++cc) {
        float4 v4 = *(const float4*)&Vs[4 * c4 + cc][4 * tx];
        const float vv[4] = {v4.x, v4.y, v4.z, v4.w};
        #pragma unroll
        for (int i = 0; i < 4; ++i)
          #pragma unroll
          for (int j = 0; j < 4; ++j)
            oa[i][j] += pr[i][cc] * vv[j];
      }
    }
  }

  // epilogue: normalize, write att in [B,T,H,D] == [B,T,E] layout
  #pragma unroll
  for (int i = 0; i < 4; ++i) {
    const float inv = 1.f / l_i[i];
    const int t = t0 + 4 * ty + i;
    float4 o = make_float4(oa[i][0] * inv, oa[i][1] * inv,
                           oa[i][2] * inv, oa[i][3] * inv);
    *(float4*)(O + headbase + (size_t)t * (NHEAD * HD) + 4 * tx) = o;
  }
}

// ---------------------------------------------------------------------------
// Inputs: 0:x 1:mask(ignored, causal computed analytically) 2:Wq 3:bq 4:Wk
//         5:bk 6:Wv 7:bv 8:Wo 9:bo
// Workspace: q,k,v,att each MTOT*EMB fp32 = 32 MiB -> 128 MiB total.
// ---------------------------------------------------------------------------
extern "C" void kernel_launch(void* const* d_in, const int* in_sizes, int n_in,
                              void* d_out, int out_size, void* d_ws, size_t ws_size,
                              hipStream_t stream) {
  (void)in_sizes; (void)n_in; (void)out_size; (void)ws_size;
  const float* x  = (const float*)d_in[0];
  const float* Wq = (const float*)d_in[2];
  const float* bq = (const float*)d_in[3];
  const float* Wk = (const float*)d_in[4];
  const float* bk = (const float*)d_in[5];
  const float* Wv = (const float*)d_in[6];
  const float* bv = (const float*)d_in[7];
  const float* Wo = (const float*)d_in[8];
  const float* bo = (const float*)d_in[9];

  float* q   = (float*)d_ws;
  float* k   = q + (size_t)MTOT * EMB;
  float* v   = k + (size_t)MTOT * EMB;
  float* att = v + (size_t)MTOT * EMB;
  float* out = (float*)d_out;

  qkv_gemm_kernel<<<dim3(MTOT / 64, EMB / 64, 3), 256, 0, stream>>>(
      x, Wq, bq, Wk, bk, Wv, bv, q, k, v);
  flash_attn_kernel<<<dim3(SEQ / 64, NBATCH * NHEAD), 256, 0, stream>>>(
      q, k, v, att);
  proj_gemm_kernel<<<dim3(MTOT / 64, EMB / 64), 256, 0, stream>>>(
      att, Wo, bo, out);
}

// Round 3
// 252.216 us; speedup vs baseline: 8.8756x; 8.8756x over previous
//
#include <hip/hip_runtime.h>

#define SEQ   2048
#define NH    16
#define HD    64
#define EMB   1024
#define NB    4
#define MTOT  (NB*SEQ)   // 8192

typedef _Float16 f16;
typedef _Float16 f16x4 __attribute__((ext_vector_type(4)));
typedef _Float16 f16x8 __attribute__((ext_vector_type(8)));
typedef float    f32x4 __attribute__((ext_vector_type(4)));

#define MFMA_F16(a,b,c) __builtin_amdgcn_mfma_f32_16x16x32_f16(a,b,c,0,0,0)

// global -> LDS direct (16B per lane). LDS dst is wave-uniform base + lane*16.
__device__ __forceinline__ void gload16(const f16* g, f16* l) {
  __builtin_amdgcn_global_load_lds(
      (const __attribute__((address_space(1))) void*)g,
      (__attribute__((address_space(3))) void*)l, 16, 0, 0);
}

// ---------------------------------------------------------------------------
// Prep: cast x (fp32) -> fp16
// ---------------------------------------------------------------------------
__global__ __launch_bounds__(256) void cast_x_kernel(
    const float* __restrict__ x, f16* __restrict__ xh) {
  size_t i = ((size_t)blockIdx.x * 256 + threadIdx.x) * 8;
  float4 a = *(const float4*)(x + i);
  float4 b = *(const float4*)(x + i + 4);
  f16x8 o;
  o[0]=(f16)a.x; o[1]=(f16)a.y; o[2]=(f16)a.z; o[3]=(f16)a.w;
  o[4]=(f16)b.x; o[5]=(f16)b.y; o[6]=(f16)b.z; o[7]=(f16)b.w;
  *(f16x8*)(xh + i) = o;
}

// ---------------------------------------------------------------------------
// Prep: Wt[n][k] = (f16) W[k][n]   (64x64 tiles through LDS)
// ---------------------------------------------------------------------------
__global__ __launch_bounds__(256) void wtrans_kernel(
    const float* __restrict__ W0, const float* __restrict__ W1,
    const float* __restrict__ W2, const float* __restrict__ W3,
    f16* __restrict__ O0, f16* __restrict__ O1,
    f16* __restrict__ O2, f16* __restrict__ O3) {
  const int z = blockIdx.z;
  const float* W = (z==0)?W0:(z==1)?W1:(z==2)?W2:W3;
  f16* O        = (z==0)?O0:(z==1)?O1:(z==2)?O2:O3;
  __shared__ float Tl[64][68];
  const int t = threadIdx.x;
  const int k0 = blockIdx.x * 64, n0 = blockIdx.y * 64;
  {
    const int r = t >> 2, c0 = (t & 3) * 16;
    const float* src = W + (size_t)(k0 + r) * EMB + n0 + c0;
    #pragma unroll
    for (int j = 0; j < 4; ++j) {
      float4 v = *(const float4*)(src + 4 * j);
      Tl[c0+4*j+0][r]=v.x; Tl[c0+4*j+1][r]=v.y;
      Tl[c0+4*j+2][r]=v.z; Tl[c0+4*j+3][r]=v.w;
    }
  }
  __syncthreads();
  {
    const int n = t >> 2, c0 = (t & 3) * 16;
    f16* dst = O + (size_t)(n0 + n) * EMB + k0 + c0;
    #pragma unroll
    for (int j = 0; j < 2; ++j) {
      f16x8 o;
      #pragma unroll
      for (int u = 0; u < 8; ++u) o[u] = (f16)Tl[n][c0 + 8*j + u];
      *(f16x8*)(dst + 8 * j) = o;
    }
  }
}

// ---------------------------------------------------------------------------
// fp16 NT GEMM core: C[m][n] = sum_k A[m][k] * Bt[n][k] + bias[n]
// 128x128 tile, BK=64, 4 waves of 64x64, global_load_lds + XOR-swizzled LDS.
// MODE 0: out f16 [B,H,T,D] (q/k)   MODE 1: out f16 [B,H,D,T] (v transposed)
// MODE 2: out f32 row-major [M,N]
// ---------------------------------------------------------------------------
template<int MODE>
__device__ __forceinline__ void gemm_core(
    const f16* __restrict__ A, const f16* __restrict__ Bt,
    const float* __restrict__ bias, void* __restrict__ out,
    int m0, int n0) {
  __shared__ f16 As[128 * 64];
  __shared__ f16 Bs[128 * 64];
  const int tid  = threadIdx.x;
  const int lane = tid & 63, w = tid >> 6;
  const int g = lane >> 4, lx = lane & 15;
  const int wr = w >> 1, wc = w & 1;
  const int sr = lane >> 3, sc = lane & 7;

  f32x4 acc[4][4];
  const f32x4 z4 = {0.f, 0.f, 0.f, 0.f};
  #pragma unroll
  for (int i = 0; i < 4; ++i)
    #pragma unroll
    for (int j = 0; j < 4; ++j) acc[i][j] = z4;

  for (int k0 = 0; k0 < EMB; k0 += 64) {
    __syncthreads();
    // stage A[128][64] and Bt-tile[128][64]: 16 chunks each, 4 per wave.
    // physical chunk (lane&7) holds logical chunk (lane&7)^(row&7)  (swizzle)
    #pragma unroll
    for (int ci = 0; ci < 4; ++ci) {
      const int i = 4 * w + ci;
      const int r = i * 8 + sr;
      const int c = sc ^ (r & 7);
      gload16(A  + (size_t)(m0 + r) * EMB + k0 + c * 8, &As[i * 512]);
      gload16(Bt + (size_t)(n0 + r) * EMB + k0 + c * 8, &Bs[i * 512]);
    }
    __syncthreads();

    #pragma unroll
    for (int h = 0; h < 2; ++h) {
      f16x8 af[4], bf[4];
      #pragma unroll
      for (int mf = 0; mf < 4; ++mf) {
        const int row = wr * 64 + mf * 16 + lx;
        const int off = (row * 128 + h * 64 + g * 16) ^ ((row & 7) << 4);
        af[mf] = *(const f16x8*)((const char*)As + off);
      }
      #pragma unroll
      for (int nf = 0; nf < 4; ++nf) {
        const int row = wc * 64 + nf * 16 + lx;
        const int off = (row * 128 + h * 64 + g * 16) ^ ((row & 7) << 4);
        bf[nf] = *(const f16x8*)((const char*)Bs + off);
      }
      #pragma unroll
      for (int mf = 0; mf < 4; ++mf)
        #pragma unroll
        for (int nf = 0; nf < 4; ++nf)
          acc[mf][nf] = MFMA_F16(af[mf], bf[nf], acc[mf][nf]);
    }
  }

  // epilogue: C/D layout col = lane&15, row = (lane>>4)*4 + reg
  #pragma unroll
  for (int mf = 0; mf < 4; ++mf) {
    #pragma unroll
    for (int nf = 0; nf < 4; ++nf) {
      const int n  = n0 + wc * 64 + nf * 16 + lx;
      const int mb = m0 + wr * 64 + mf * 16 + g * 4;
      const float bv = bias[n];
      if (MODE == 2) {
        float* op = (float*)out;
        #pragma unroll
        for (int r = 0; r < 4; ++r)
          op[(size_t)(mb + r) * EMB + n] = acc[mf][nf][r] + bv;
      } else {
        const int b = mb >> 11, tt = mb & (SEQ - 1);
        const int hh = n >> 6, d = n & (HD - 1);
        f16* op = (f16*)out;
        if (MODE == 0) {
          #pragma unroll
          for (int r = 0; r < 4; ++r)
            op[((size_t)(b * NH + hh) * SEQ + tt + r) * HD + d] =
                (f16)(acc[mf][nf][r] + bv);
        } else {
          f16x4 o;
          #pragma unroll
          for (int r = 0; r < 4; ++r) o[r] = (f16)(acc[mf][nf][r] + bv);
          *(f16x4*)(op + ((size_t)(b * NH + hh) * HD + d) * SEQ + tt) = o;
        }
      }
    }
  }
}

__global__ __launch_bounds__(256) void qk_gemm_kernel(
    const f16* __restrict__ xh, const f16* __restrict__ wqt,
    const f16* __restrict__ wkt, const float* __restrict__ bq,
    const float* __restrict__ bk, f16* __restrict__ qh, f16* __restrict__ kh) {
  const int z = blockIdx.z;
  gemm_core<0>(xh, z ? wkt : wqt, z ? bk : bq, z ? kh : qh,
               blockIdx.x * 128, blockIdx.y * 128);
}

__global__ __launch_bounds__(256) void v_gemm_kernel(
    const f16* __restrict__ xh, const f16* __restrict__ wvt,
    const float* __restrict__ bv, f16* __restrict__ vth) {
  gemm_core<1>(xh, wvt, bv, vth, blockIdx.x * 128, blockIdx.y * 128);
}

__global__ __launch_bounds__(256) void proj_gemm_kernel(
    const f16* __restrict__ ath, const f16* __restrict__ wot,
    const float* __restrict__ bo, float* __restrict__ out) {
  gemm_core<2>(ath, wot, bo, out, blockIdx.x * 128, blockIdx.y * 128);
}

// ---------------------------------------------------------------------------
// Causal flash attention, fp16 MFMA.
// q,k: [B,H,T,D]; v: [B,H,D,T]; out att: [B,T,E] f16.
// Block = 4 waves; Q tile = 64 rows (16/wave); KV tile = 64.
// Swapped QK^T (mfma(K,Q)) -> lane owns P row qr = lane&15 (16 scores/tile).
// P transposed into per-wave LDS, PV via Vt. All LDS XOR-swizzled.
// ---------------------------------------------------------------------------
__global__ __launch_bounds__(256) void attn_kernel(
    const f16* __restrict__ Qh, const f16* __restrict__ Kh,
    const f16* __restrict__ Vth, f16* __restrict__ Att) {
  __shared__ f16 Ks[64 * 64];
  __shared__ f16 Vs[64 * 64];
  __shared__ f16 Ps[4][16 * 64];
  const int tid  = threadIdx.x;
  const int lane = tid & 63, w = tid >> 6;
  const int g = lane >> 4, lx = lane & 15;
  const int sr = lane >> 3, sc = lane & 7;
  const int qt = (int)gridDim.x - 1 - (int)blockIdx.x;   // heavy tiles first
  const int bh = blockIdx.y;
  const int t0 = qt * 64;
  const f16* qp = Qh  + (size_t)bh * SEQ * HD;
  const f16* kp = Kh  + (size_t)bh * SEQ * HD;
  const f16* vp = Vth + (size_t)bh * HD * SEQ;
  const int qrow = t0 + w * 16 + lx;   // this lane's q row

  // Q fragments (B-operand), loop-invariant: Q[qrow][d = h*32 + g*8 + i]
  f16x8 qf[2];
  #pragma unroll
  for (int h = 0; h < 2; ++h)
    qf[h] = *(const f16x8*)(qp + (size_t)qrow * HD + h * 32 + g * 8);

  const f32x4 z4 = {0.f, 0.f, 0.f, 0.f};
  f32x4 oa[4];
  #pragma unroll
  for (int df = 0; df < 4; ++df) oa[df] = z4;
  float m_i = -1e30f, l_i = 0.f;

  for (int kt = 0; kt <= qt; ++kt) {
    __syncthreads();
    // stage K[64][64] (rows=kv) and Vt[64][64] (rows=d), 8 chunks each
    #pragma unroll
    for (int ci = 0; ci < 2; ++ci) {
      const int i = 2 * w + ci;
      const int r = i * 8 + sr;
      const int c = sc ^ (r & 7);
      gload16(kp + (size_t)(kt * 64 + r) * HD + c * 8, &Ks[i * 512]);
      gload16(vp + (size_t)r * SEQ + kt * 64 + c * 8,  &Vs[i * 512]);
    }
    __syncthreads();

    // S' = K . Q^T : S'[kv][qr], lane reg r of frag sf: kv = sf*16+g*4+r, qr = lx
    f32x4 sa[4];
    #pragma unroll
    for (int sf = 0; sf < 4; ++sf) sa[sf] = z4;
    #pragma unroll
    for (int h = 0; h < 2; ++h)
      #pragma unroll
      for (int sf = 0; sf < 4; ++sf) {
        const int row = sf * 16 + lx;
        const int off = (row * 128 + h * 64 + g * 16) ^ ((row & 7) << 4);
        f16x8 kf = *(const f16x8*)((const char*)Ks + off);
        sa[sf] = MFMA_F16(kf, qf[h], sa[sf]);
      }

    // scale + causal mask + online softmax (row qrow lives in lanes lx,+16,+32,+48)
    float sv[16];
    float rmax = -1e30f;
    const bool diag = (kt == qt);
    #pragma unroll
    for (int sf = 0; sf < 4; ++sf)
      #pragma unroll
      for (int r = 0; r < 4; ++r) {
        const int kv = kt * 64 + sf * 16 + g * 4 + r;
        float vsc = sa[sf][r] * 0.125f;
        if (diag && kv > qrow) vsc = -1e30f;
        sv[sf * 4 + r] = vsc;
        rmax = fmaxf(rmax, vsc);
      }
    rmax = fmaxf(rmax, __shfl_xor(rmax, 16));
    rmax = fmaxf(rmax, __shfl_xor(rmax, 32));
    const float mnew = fmaxf(m_i, rmax);
    const float corr = __expf(m_i - mnew);
    m_i = mnew;
    float rsum = 0.f;
    #pragma unroll
    for (int u = 0; u < 16; ++u) {
      const float p = __expf(sv[u] - mnew);
      sv[u] = p;
      rsum += p;
    }
    rsum += __shfl_xor(rsum, 16);
    rsum += __shfl_xor(rsum, 32);
    l_i = l_i * corr + rsum;

    // P -> LDS transposed to [qr][kv] (swizzled); regs r=0..3 are kv-contiguous
    #pragma unroll
    for (int sf = 0; sf < 4; ++sf) {
      f16x4 p4;
      #pragma unroll
      for (int r = 0; r < 4; ++r) p4[r] = (f16)sv[sf * 4 + r];
      const int off = (lx * 128 + sf * 32 + g * 8) ^ ((lx & 7) << 4);
      *(f16x4*)((char*)Ps[w] + off) = p4;
    }

    // rescale O (O rows qr' = g*4+r; corr for row q lives in lane q (q<16))
    #pragma unroll
    for (int r = 0; r < 4; ++r) {
      const float cr = __shfl(corr, g * 4 + r, 64);
      #pragma unroll
      for (int df = 0; df < 4; ++df) oa[df][r] *= cr;
    }

    // O += P @ V   (A = P from LDS, B = Vt rows)
    #pragma unroll
    for (int hk = 0; hk < 2; ++hk) {
      const int offp = (lx * 128 + hk * 64 + g * 16) ^ ((lx & 7) << 4);
      f16x8 pf = *(const f16x8*)((const char*)Ps[w] + offp);
      #pragma unroll
      for (int df = 0; df < 4; ++df) {
        const int row = df * 16 + lx;
        const int offv = (row * 128 + hk * 64 + g * 16) ^ ((row & 7) << 4);
        f16x8 vf = *(const f16x8*)((const char*)Vs + offv);
        oa[df] = MFMA_F16(pf, vf, oa[df]);
      }
    }
  }

  // epilogue: normalize rows, write att [B,T,E] f16
  const int b = bh >> 4, hh = bh & 15;
  const float inv = 1.f / l_i;
  #pragma unroll
  for (int r = 0; r < 4; ++r) {
    const float ir = __shfl(inv, g * 4 + r, 64);
    const int t = t0 + w * 16 + g * 4 + r;
    f16* dst = Att + ((size_t)b * SEQ + t) * EMB + hh * HD;
    #pragma unroll
    for (int df = 0; df < 4; ++df)
      dst[df * 16 + lx] = (f16)(oa[df][r] * ir);
  }
}

// ---------------------------------------------------------------------------
// inputs: 0:x 1:mask(ignored) 2:Wq 3:bq 4:Wk 5:bk 6:Wv 7:bv 8:Wo 9:bo
// ws: xh 16MB | wqt,wkt,wvt,wot 2MB ea | qh,kh,vth,ath 16MB ea  = 88MB
// ---------------------------------------------------------------------------
extern "C" void kernel_launch(void* const* d_in, const int* in_sizes, int n_in,
                              void* d_out, int out_size, void* d_ws, size_t ws_size,
                              hipStream_t stream) {
  (void)in_sizes; (void)n_in; (void)out_size; (void)ws_size;
  const float* x  = (const float*)d_in[0];
  const float* Wq = (const float*)d_in[2];
  const float* bq = (const float*)d_in[3];
  const float* Wk = (const float*)d_in[4];
  const float* bk = (const float*)d_in[5];
  const float* Wv = (const float*)d_in[6];
  const float* bv = (const float*)d_in[7];
  const float* Wo = (const float*)d_in[8];
  const float* bo = (const float*)d_in[9];

  f16* xh  = (f16*)d_ws;
  f16* wqt = xh  + (size_t)MTOT * EMB;
  f16* wkt = wqt + (size_t)EMB * EMB;
  f16* wvt = wkt + (size_t)EMB * EMB;
  f16* wot = wvt + (size_t)EMB * EMB;
  f16* qh  = wot + (size_t)EMB * EMB;
  f16* kh  = qh  + (size_t)MTOT * EMB;
  f16* vth = kh  + (size_t)MTOT * EMB;
  f16* ath = vth + (size_t)MTOT * EMB;

  cast_x_kernel<<<dim3(MTOT * EMB / (256 * 8)), 256, 0, stream>>>(x, xh);
  wtrans_kernel<<<dim3(16, 16, 4), 256, 0, stream>>>(
      Wq, Wk, Wv, Wo, wqt, wkt, wvt, wot);
  qk_gemm_kernel<<<dim3(MTOT / 128, EMB / 128, 2), 256, 0, stream>>>(
      xh, wqt, wkt, bq, bk, qh, kh);
  v_gemm_kernel<<<dim3(MTOT / 128, EMB / 128), 256, 0, stream>>>(
      xh, wvt, bv, vth);
  attn_kernel<<<dim3(SEQ / 64, NB * NH), 256, 0, stream>>>(qh, kh, vth, ath);
  proj_gemm_kernel<<<dim3(MTOT / 128, EMB / 128), 256, 0, stream>>>(
      ath, wot, bo, (float*)d_out);
}